// Round 1
// 427.659 us; speedup vs baseline: 1.0102x; 1.0102x over previous
//
#include <hip/hip_runtime.h>

// STDP plasticity: out = clip(W + (LR/B) * post^T @ pre, 0, 1)
// W: [8192 x 8192] fp32, pre/post: [32 x 8192] fp32.
// Memory-bound streaming kernel: 256 MB W-read + 256 MB out-write.
// R3: convoy elimination. R2 was strictly phased (stage -> 2048 FMAs with
// HBM idle -> 16-load/16-store burst). Restructured into 4 row-groups of 4
// with double-buffered W prefetch: group 0's W loads issue at t=0 (before
// staging), group g+1's loads issue before group g's batch loop, each
// group stores immediately after its FMAs. HBM read+write traffic is now
// spread across the whole kernel lifetime instead of bursting at the end.
// acc shrinks 64->16 VGPRs (+32 for the two W buffers) -> stays <=128 VGPR,
// 4 waves/SIMD; LDS 40 KB -> 4 blocks/CU.
// Per batch iter: 1 dense ds_read_b128 (pre) + 1 broadcast (post) + 16 FMA.

#define DIM    8192
#define BATCH  32
#define SCALE  (0.01f / 32.0f)   // LR / B

#define BTO 64    // block tile rows (o)
#define BTI 256   // block tile cols (i)

typedef __attribute__((ext_vector_type(4))) float f4;

__global__ __launch_bounds__(256) void stdp_update_kernel(
    const float* __restrict__ W,
    const float* __restrict__ pre,
    const float* __restrict__ post,
    float* __restrict__ out)
{
    __shared__ float pr_s[BATCH][BTI];   // 32 KB
    __shared__ float po_s[BATCH][BTO];   //  8 KB

    const int tid = threadIdx.x;
    const int i0  = blockIdx.x * BTI;
    const int o0  = blockIdx.y * BTO;

    const int ci = (tid & 63) << 2;   // i offset: one float4 per lane, dense across wave
    const int og = (tid >> 6) << 4;   // o offset: 16 rows per wave-group (wave-uniform)

    // This lane's base element: row (o0+og), col (i0+ci).
    const size_t base = (size_t)(o0 + og) * DIM + i0 + ci;

    // Prefetch W rows for group 0 immediately: HBM read stream starts at
    // t=0, before staging and compute. Each instruction: 64 lanes x 16 B
    // = 1 KB dense.
    f4 wA[4], wB[4];
    #pragma unroll
    for (int r = 0; r < 4; ++r)
        wA[r] = __builtin_nontemporal_load((const f4*)(W + base + (size_t)r * DIM));

    // Stage pre tile: 32 x 256 floats = 2048 float4, 8 per thread.
    // One wave covers exactly one 1 KB row segment -> fully coalesced.
    #pragma unroll
    for (int k = 0; k < 8; ++k) {
        const int idx = tid + k * 256;
        const int row = idx >> 6;           // 64 float4 per row
        const int c4  = (idx & 63) << 2;
        *(f4*)&pr_s[row][c4] = *(const f4*)&pre[(size_t)row * DIM + i0 + c4];
    }
    // Stage post tile: 32 x 64 floats = 512 float4, 2 per thread.
    #pragma unroll
    for (int k = 0; k < 2; ++k) {
        const int idx = tid + k * 256;
        const int row = idx >> 4;           // 16 float4 per row
        const int c4  = (idx & 15) << 2;
        *(f4*)&po_s[row][c4] = *(const f4*)&post[(size_t)row * DIM + o0 + c4];
    }
    __syncthreads();

    // 4 row-groups of 4 rows each; W double-buffered across groups.
    #pragma unroll
    for (int g = 0; g < 4; ++g) {
        // Issue next group's W loads before this group's compute: one full
        // batch loop (~1.3k cyc) covers HBM latency (~900 cyc).
        if (g < 3) {
            #pragma unroll
            for (int r = 0; r < 4; ++r)
                wB[r] = __builtin_nontemporal_load(
                    (const f4*)(W + base + (size_t)((g + 1) * 4 + r) * DIM));
        }

        float acc[4][4];
        #pragma unroll
        for (int r = 0; r < 4; ++r)
            #pragma unroll
            for (int c = 0; c < 4; ++c)
                acc[r][c] = 0.0f;

        #pragma unroll 8
        for (int b = 0; b < BATCH; ++b) {
            const f4 p = *(const f4*)&pr_s[b][ci];            // dense, conflict-free
            const f4 q = *(const f4*)&po_s[b][og + g * 4];    // wave-uniform broadcast
            #pragma unroll
            for (int r = 0; r < 4; ++r)
                #pragma unroll
                for (int c = 0; c < 4; ++c)
                    acc[r][c] = fmaf(q[r], p[c], acc[r][c]);
        }

        // Per-group epilogue: stores spread across kernel lifetime.
        // Each instruction is 64 lanes x 16 B contiguous = 1 KB dense.
        #pragma unroll
        for (int r = 0; r < 4; ++r) {
            const size_t off = base + (size_t)(g * 4 + r) * DIM;
            f4 r4;
            r4.x = fminf(fmaxf(fmaf(SCALE, acc[r][0], wA[r].x), 0.0f), 1.0f);
            r4.y = fminf(fmaxf(fmaf(SCALE, acc[r][1], wA[r].y), 0.0f), 1.0f);
            r4.z = fminf(fmaxf(fmaf(SCALE, acc[r][2], wA[r].z), 0.0f), 1.0f);
            r4.w = fminf(fmaxf(fmaf(SCALE, acc[r][3], wA[r].w), 0.0f), 1.0f);
            __builtin_nontemporal_store(r4, (f4*)(out + off));
        }

        // Rotate double buffer (fully unrolled -> pure register renaming).
        #pragma unroll
        for (int r = 0; r < 4; ++r) wA[r] = wB[r];
    }
}

extern "C" void kernel_launch(void* const* d_in, const int* in_sizes, int n_in,
                              void* d_out, int out_size, void* d_ws, size_t ws_size,
                              hipStream_t stream) {
    const float* W    = (const float*)d_in[0];
    const float* pre  = (const float*)d_in[1];
    const float* post = (const float*)d_in[2];
    float*       out  = (float*)d_out;

    dim3 grid(DIM / BTI, DIM / BTO);   // 32 x 128 = 4096 blocks
    stdp_update_kernel<<<grid, 256, 0, stream>>>(W, pre, post, out);
}